// Round 2
// baseline (2330.393 us; speedup 1.0000x reference)
//
#include <hip/hip_runtime.h>
#include <stdint.h>
#include <stddef.h>

#define BB 4
#define LL 2048
#define DD 1024
#define HH 16
#define DKK 64
#define DFFN 4096

typedef __bf16 bf16;
typedef __attribute__((ext_vector_type(4))) float f32x4;
typedef __attribute__((ext_vector_type(8))) bf16 bf16x8;
typedef __attribute__((ext_vector_type(4))) bf16 bf16x4;

// ---------------------------------------------------------------- async copy
__device__ __forceinline__ void async_ld16(const void* g, void* l) {
  __builtin_amdgcn_global_load_lds(
      (const __attribute__((address_space(1))) void*)g,
      (__attribute__((address_space(3))) void*)l, 16, 0, 0);
}

// ---------------------------------------------------------------- fp32->bf16
__global__ __launch_bounds__(256) void cvt_kernel(
    const float* __restrict__ in, bf16* __restrict__ out, int n4) {
  int i = blockIdx.x * 256 + threadIdx.x;
  if (i >= n4) return;
  f32x4 v = ((const f32x4*)in)[i];
  bf16x4 o;
  o[0] = (bf16)v.x; o[1] = (bf16)v.y; o[2] = (bf16)v.z; o[3] = (bf16)v.w;
  ((bf16x4*)out)[i] = o;
}

// ---------------------------------------------------------------- layernorm
__global__ __launch_bounds__(256) void ln_kernel(
    const float* __restrict__ x, const float* __restrict__ gam,
    const float* __restrict__ bet, bf16* __restrict__ out) {
  int row = blockIdx.x;
  const float* xr = x + (size_t)row * DD;
  int t = threadIdx.x, wave = t >> 6, lane = t & 63;
  f32x4 v = *(const f32x4*)(xr + (t << 2));
  float s = v.x + v.y + v.z + v.w;
  float q2 = v.x * v.x + v.y * v.y + v.z * v.z + v.w * v.w;
#pragma unroll
  for (int off = 32; off; off >>= 1) {
    s += __shfl_xor(s, off);
    q2 += __shfl_xor(q2, off);
  }
  __shared__ float a1[4], a2[4];
  if (lane == 0) { a1[wave] = s; a2[wave] = q2; }
  __syncthreads();
  s = a1[0] + a1[1] + a1[2] + a1[3];
  q2 = a2[0] + a2[1] + a2[2] + a2[3];
  float mean = s * (1.0f / DD);
  float var = q2 * (1.0f / DD) - mean * mean;
  float rs = rsqrtf(var + 1e-6f);
  f32x4 g = *(const f32x4*)(gam + (t << 2));
  f32x4 b = *(const f32x4*)(bet + (t << 2));
  bf16x4 o;
  o[0] = (bf16)((v.x - mean) * rs * g.x + b.x);
  o[1] = (bf16)((v.y - mean) * rs * g.y + b.y);
  o[2] = (bf16)((v.z - mean) * rs * g.z + b.z);
  o[3] = (bf16)((v.w - mean) * rs * g.w + b.w);
  *(bf16x4*)&out[(size_t)row * DD + (t << 2)] = o;
}

// ---------------------------------------------------------------- BT GEMM
// C[M,N] = A[M,K] * B[N,K]^T.  BM=128 fixed, BK=32, 4 waves (2x2).
template <int BN, bool AF32, bool OUTF32, bool HASBIAS, bool DORELU,
          bool HASRES, bool PVMODE>
__global__ __launch_bounds__(256, 2) void gemm_bt(
    const void* __restrict__ Ain, const bf16* __restrict__ Bm,
    void* __restrict__ Cout, const float* __restrict__ bias,
    const float* __restrict__ res, int K, int ldc) {
  constexpr int BM = 128, BK = 32;
  constexpr int WN = BN / 32;  // j-tiles per wave
  static_assert(BN == 64 || BN == 128, "BN");
  __shared__ bf16 As[BM * BK];
  __shared__ bf16 Bs[BN * BK];
  int tid = threadIdx.x;
  int wave = tid >> 6, lane = tid & 63;
  int quad = lane >> 4, lm = lane & 15;
  int wm = wave & 1, wn = wave >> 1;
  int m0 = blockIdx.x * BM;
  int n0 = PVMODE ? 0 : blockIdx.y * BN;

  const bf16* Ab = (const bf16*)Ain;
  const float* Af = (const float*)Ain;
  size_t c_off = 0;
  if constexpr (PVMODE) {
    int pb = blockIdx.y;   // batch  (gridDim.y = 4)
    int ph = blockIdx.z;   // head   (gridDim.z = 16)
    size_t bh = (size_t)(pb * HH + ph);
    Af += bh * (size_t)LL * LL;        // attn probs fp32, per-head
    Bm += bh * (size_t)DKK * LL;       // vT, per-head
    c_off = (size_t)pb * ((size_t)LL * DD) + (size_t)ph * DKK;
  }

  f32x4 acc[4][WN];
#pragma unroll
  for (int i = 0; i < 4; i++)
#pragma unroll
    for (int j = 0; j < WN; j++) acc[i][j] = (f32x4)0.0f;

  for (int k0 = 0; k0 < K; k0 += BK) {
    __syncthreads();
    // ---- stage A tile (128 x 32)
    if constexpr (AF32) {
#pragma unroll
      for (int it = 0; it < 2; ++it) {
        int chunk = tid + it * 256;  // 0..511, 8 elems each
        int row = chunk >> 2;
        int kc = (chunk & 3) << 3;
        const float* sp = Af + (size_t)(m0 + row) * K + k0 + kc;
        f32x4 u0 = *(const f32x4*)sp;
        f32x4 u1 = *(const f32x4*)(sp + 4);
        bf16x8 wv;
        wv[0] = (bf16)u0.x; wv[1] = (bf16)u0.y; wv[2] = (bf16)u0.z; wv[3] = (bf16)u0.w;
        wv[4] = (bf16)u1.x; wv[5] = (bf16)u1.y; wv[6] = (bf16)u1.z; wv[7] = (bf16)u1.w;
        *(bf16x8*)&As[chunk << 3] = wv;
      }
    } else {
#pragma unroll
      for (int it = 0; it < 2; ++it) {
        int chunk = it * 256 + (wave << 6) + lane;
        int row = chunk >> 2;
        int kc = (chunk & 3) << 3;
        async_ld16(Ab + (size_t)(m0 + row) * K + k0 + kc, &As[chunk << 3]);
      }
    }
    // ---- stage B tile (BN x 32)
#pragma unroll
    for (int it = 0; it < BN / 64; ++it) {
      int chunk = it * 256 + (wave << 6) + lane;
      int row = chunk >> 2;
      int kc = (chunk & 3) << 3;
      async_ld16(Bm + (size_t)(n0 + row) * K + k0 + kc, &Bs[chunk << 3]);
    }
    __syncthreads();
    // ---- fragments + MFMA
    bf16x8 af[4], bfr[WN];
#pragma unroll
    for (int i = 0; i < 4; i++)
      af[i] = *(const bf16x8*)&As[(((wm << 6) + (i << 4) + lm) << 5) + (quad << 3)];
#pragma unroll
    for (int j = 0; j < WN; j++)
      bfr[j] = *(const bf16x8*)&Bs[((wn * (BN / 2) + (j << 4) + lm) << 5) + (quad << 3)];
#pragma unroll
    for (int i = 0; i < 4; i++)
#pragma unroll
      for (int j = 0; j < WN; j++)
        acc[i][j] = __builtin_amdgcn_mfma_f32_16x16x32_bf16(af[i], bfr[j], acc[i][j], 0, 0, 0);
  }

  // ---- epilogue
  float* Cf = (float*)Cout;
  bf16* Cb = (bf16*)Cout;
#pragma unroll
  for (int i = 0; i < 4; i++) {
    int rowb = m0 + (wm << 6) + (i << 4) + (quad << 2);
#pragma unroll
    for (int r = 0; r < 4; r++) {
      int row = rowb + r;
#pragma unroll
      for (int j = 0; j < WN; j++) {
        int col = n0 + wn * (BN / 2) + (j << 4) + lm;
        float v = acc[i][j][r];
        if constexpr (HASBIAS) v += bias[col];
        if constexpr (DORELU) v = fmaxf(v, 0.0f);
        if constexpr (HASRES) v += res[(size_t)row * ldc + col];
        size_t cidx = c_off + (size_t)row * ldc + col;
        if constexpr (OUTF32) Cf[cidx] = v;
        else Cb[cidx] = (bf16)v;
      }
    }
  }
}

// ---------------------------------------------------------------- split q/k
__global__ __launch_bounds__(256) void split_qk(
    const bf16* __restrict__ qkv, bf16* __restrict__ qh, bf16* __restrict__ kh) {
  int idx = blockIdx.x * 256 + threadIdx.x;  // chunk of 8
  int f = idx << 3;                          // flat in [8192,1024]
  int m = f >> 10, c = f & 1023;
  int b = m >> 11, l = m & 2047;
  int h = c >> 6, d = c & 63;
  size_t srcq = (size_t)m * 3072 + c;
  size_t dst = ((size_t)(b * HH + h) * LL + l) * DKK + d;
  bf16x8 qv = *(const bf16x8*)&qkv[srcq];
#pragma unroll
  for (int e = 0; e < 8; e++) qv[e] = (bf16)((float)qv[e] * 0.125f);
  *(bf16x8*)&qh[dst] = qv;
  *(bf16x8*)&kh[dst] = *(const bf16x8*)&qkv[srcq + 1024];
}

// ---------------------------------------------------------------- v -> vT
__global__ __launch_bounds__(256) void transpose_v(
    const bf16* __restrict__ qkv, bf16* __restrict__ vt) {
  __shared__ bf16 tile[64][65];
  int bh = blockIdx.y;
  int b = bh >> 4, h = bh & 15;
  int l0 = blockIdx.x << 6;
  int t = threadIdx.x;
  int d = t & 63, r = t >> 6;  // r in 0..3
#pragma unroll
  for (int i = 0; i < 16; i++) {
    int l = (i << 2) + r;
    tile[l][d] = qkv[((size_t)(b * LL) + l0 + l) * 3072 + 2048 + (h << 6) + d];
  }
  __syncthreads();
#pragma unroll
  for (int i = 0; i < 16; i++) {
    int dd = (i << 2) + r;
    vt[((size_t)bh * DKK + dd) * LL + l0 + d] = tile[d][dd];
  }
}

// ---------------------------------------------------------------- scores
// S[b,h,q,k] = (q . k) * prior[b,q,k], masked.  K=64: direct-from-global frags.
__global__ __launch_bounds__(256) void score_kernel(
    const bf16* __restrict__ qh, const bf16* __restrict__ kh,
    const float* __restrict__ prior, const int* __restrict__ mask,
    float* __restrict__ Sout) {
  int bh = blockIdx.z;
  int b = bh >> 4;
  const bf16* q = qh + (size_t)bh * LL * DKK;
  const bf16* k = kh + (size_t)bh * LL * DKK;
  float* S = Sout + (size_t)bh * LL * LL;
  const float* pr = prior + (size_t)b * LL * LL;
  const int* mk = mask + b * LL;
  int tid = threadIdx.x, wave = tid >> 6, lane = tid & 63;
  int quad = lane >> 4, lm = lane & 15;
  int wm = wave & 1, wn = wave >> 1;
  int m0 = blockIdx.x * 128 + (wm << 6);
  int n0 = blockIdx.y * 128 + (wn << 6);
  bf16x8 a[4][2], bb[4][2];
#pragma unroll
  for (int i = 0; i < 4; i++)
#pragma unroll
    for (int ks = 0; ks < 2; ks++) {
      a[i][ks] = *(const bf16x8*)&q[(size_t)(m0 + (i << 4) + lm) * DKK + (ks << 5) + (quad << 3)];
      bb[i][ks] = *(const bf16x8*)&k[(size_t)(n0 + (i << 4) + lm) * DKK + (ks << 5) + (quad << 3)];
    }
  f32x4 acc[4][4];
#pragma unroll
  for (int i = 0; i < 4; i++)
#pragma unroll
    for (int j = 0; j < 4; j++) acc[i][j] = (f32x4)0.0f;
#pragma unroll
  for (int i = 0; i < 4; i++)
#pragma unroll
    for (int j = 0; j < 4; j++) {
      acc[i][j] = __builtin_amdgcn_mfma_f32_16x16x32_bf16(a[i][0], bb[j][0], acc[i][j], 0, 0, 0);
      acc[i][j] = __builtin_amdgcn_mfma_f32_16x16x32_bf16(a[i][1], bb[j][1], acc[i][j], 0, 0, 0);
    }
  int msk[4];
#pragma unroll
  for (int j = 0; j < 4; j++) msk[j] = mk[n0 + (j << 4) + lm];
#pragma unroll
  for (int i = 0; i < 4; i++)
#pragma unroll
    for (int r = 0; r < 4; r++) {
      int row = m0 + (i << 4) + (quad << 2) + r;
      const float* prow = pr + (size_t)row * LL;
      float* srow = S + (size_t)row * LL;
#pragma unroll
      for (int j = 0; j < 4; j++) {
        int col = n0 + (j << 4) + lm;
        float v = acc[i][j][r] * prow[col];
        v = (msk[j] == 0) ? -1e9f : v;
        srow[col] = v;
      }
    }
}

// ---------------------------------------------------------------- softmax
// One block per attention row.  B*H*L = 131072 rows, 2048 cols each.
__global__ __launch_bounds__(256) void softmax_kernel(float* __restrict__ S) {
  size_t row = blockIdx.x;
  float* p = S + row * (size_t)LL;
  int t = threadIdx.x, wave = t >> 6, lane = t & 63;
  f32x4 v0 = *(const f32x4*)(p + (t << 3));
  f32x4 v1 = *(const f32x4*)(p + (t << 3) + 4);
  float mx = fmaxf(fmaxf(fmaxf(v0.x, v0.y), fmaxf(v0.z, v0.w)),
                   fmaxf(fmaxf(v1.x, v1.y), fmaxf(v1.z, v1.w)));
#pragma unroll
  for (int off = 32; off; off >>= 1) mx = fmaxf(mx, __shfl_xor(mx, off));
  __shared__ float r1[4], r2[4];
  if (lane == 0) r1[wave] = mx;
  __syncthreads();
  mx = fmaxf(fmaxf(r1[0], r1[1]), fmaxf(r1[2], r1[3]));
  const float LOG2E = 1.44269504088896340736f;
  f32x4 e0, e1;
  e0.x = exp2f((v0.x - mx) * LOG2E); e0.y = exp2f((v0.y - mx) * LOG2E);
  e0.z = exp2f((v0.z - mx) * LOG2E); e0.w = exp2f((v0.w - mx) * LOG2E);
  e1.x = exp2f((v1.x - mx) * LOG2E); e1.y = exp2f((v1.y - mx) * LOG2E);
  e1.z = exp2f((v1.z - mx) * LOG2E); e1.w = exp2f((v1.w - mx) * LOG2E);
  float s = e0.x + e0.y + e0.z + e0.w + e1.x + e1.y + e1.z + e1.w;
#pragma unroll
  for (int off = 32; off; off >>= 1) s += __shfl_xor(s, off);
  if (lane == 0) r2[wave] = s;
  __syncthreads();
  s = r2[0] + r2[1] + r2[2] + r2[3];
  float inv = 1.0f / s;
  *(f32x4*)(p + (t << 3)) = e0 * inv;
  *(f32x4*)(p + (t << 3) + 4) = e1 * inv;
}

// ---------------------------------------------------------------- launch
extern "C" void kernel_launch(void* const* d_in, const int* in_sizes, int n_in,
                              void* d_out, int out_size, void* d_ws,
                              size_t ws_size, hipStream_t stream) {
  const float* src = (const float*)d_in[0];
  const int* mask = (const int*)d_in[1];
  const float* prior = (const float*)d_in[2];
  const float* ln1_g = (const float*)d_in[3];
  const float* ln1_b = (const float*)d_in[4];
  const float* wq = (const float*)d_in[5];
  const float* wk = (const float*)d_in[6];
  const float* wv = (const float*)d_in[7];
  const float* fc_w = (const float*)d_in[8];
  const float* ln2_g = (const float*)d_in[9];
  const float* ln2_b = (const float*)d_in[10];
  const float* w1_w = (const float*)d_in[11];
  const float* w1_b = (const float*)d_in[12];
  const float* w2_w = (const float*)d_in[13];
  const float* w2_b = (const float*)d_in[14];

  float* y_out = (float*)d_out;
  float* attn_out = y_out + (size_t)BB * LL * DD;

  // ---- workspace layout with liveness-based aliasing (~168 MB total) ----
  char* w = (char*)d_ws;
  bf16* wqkv_b = (bf16*)w;  w += (size_t)3072 * 1024 * 2;   //  6 MB persistent
  bf16* wfc_b = (bf16*)w;   w += (size_t)1024 * 1024 * 2;   //  2 MB persistent
  bf16* w1b16 = (bf16*)w;   w += (size_t)4096 * 1024 * 2;   //  8 MB persistent
  bf16* w2b16 = (bf16*)w;   w += (size_t)1024 * 4096 * 2;   //  8 MB persistent
  char* regB = w;           w += (size_t)8192 * 1024 * 2;   // 16 MB: x_b -> o_flat
  char* regC = w;           w += (size_t)8192 * 3072 * 2;   // 48 MB: qkv_flat -> z_b + h_b(head)
  char* regD = w;           w += (size_t)3 * 8388608 * 2;   // 48 MB: qh,kh,vt -> h_b(tail)
  float* y1 = (float*)w;    w += (size_t)8192 * 1024 * 4;   // 32 MB persistent (fc->end)

  bf16* x_b = (bf16*)regB;        // live: LN1 -> QKV gemm
  bf16* o_flat = (bf16*)regB;     // live: PV gemm -> fc gemm (x_b dead)
  bf16* qkv_flat = (bf16*)regC;   // live: QKV gemm -> split/transpose
  bf16* z_b = (bf16*)regC;        // live: LN2 -> FFN1 (qkv dead)
  bf16* h_b = (bf16*)(regC + (size_t)8192 * 1024 * 2);  // 64 MB spanning C-tail + qh + kh
                                   // live: FFN1 -> FFN2 (qkv, qh, kh all dead)
  bf16* qh = (bf16*)regD;
  bf16* kh = (bf16*)(regD + (size_t)8388608 * 2);
  bf16* vt = (bf16*)(regD + (size_t)2 * 8388608 * 2);

  // weights -> bf16
  cvt_kernel<<<1024, 256, 0, stream>>>(wq, wqkv_b, 262144);
  cvt_kernel<<<1024, 256, 0, stream>>>(wk, wqkv_b + 1024 * 1024, 262144);
  cvt_kernel<<<1024, 256, 0, stream>>>(wv, wqkv_b + 2 * 1024 * 1024, 262144);
  cvt_kernel<<<1024, 256, 0, stream>>>(fc_w, wfc_b, 262144);
  cvt_kernel<<<4096, 256, 0, stream>>>(w1_w, w1b16, 1048576);
  cvt_kernel<<<4096, 256, 0, stream>>>(w2_w, w2b16, 1048576);

  // LN1
  ln_kernel<<<8192, 256, 0, stream>>>(src, ln1_g, ln1_b, x_b);
  // QKV projection: [8192,1024] x [3072,1024]^T -> [8192,3072] bf16
  gemm_bt<128, false, false, false, false, false, false>
      <<<dim3(64, 24, 1), 256, 0, stream>>>(x_b, wqkv_b, qkv_flat, nullptr, nullptr, 1024, 3072);
  split_qk<<<4096, 256, 0, stream>>>(qkv_flat, qh, kh);
  transpose_v<<<dim3(32, 64, 1), 256, 0, stream>>>(qkv_flat, vt);
  // scores (+prior, +mask) -> attn region of d_out
  score_kernel<<<dim3(16, 16, 64), 256, 0, stream>>>(qh, kh, prior, mask, attn_out);
  // softmax in place: one block per row, B*H*L = 131072 rows
  softmax_kernel<<<131072, 256, 0, stream>>>(attn_out);
  // O = P @ V   (A = fp32 attn, converted during staging)
  gemm_bt<64, true, false, false, false, false, true>
      <<<dim3(16, 4, 16), 256, 0, stream>>>(attn_out, vt, o_flat, nullptr, nullptr, 2048, 1024);
  // y1 = O @ fc_w^T + src
  gemm_bt<128, false, true, false, false, true, false>
      <<<dim3(64, 8, 1), 256, 0, stream>>>(o_flat, wfc_b, y1, nullptr, src, 1024, 1024);
  // LN2
  ln_kernel<<<8192, 256, 0, stream>>>(y1, ln2_g, ln2_b, z_b);
  // h = relu(z @ w1^T + b1)
  gemm_bt<128, false, false, true, true, false, false>
      <<<dim3(64, 32, 1), 256, 0, stream>>>(z_b, w1b16, h_b, w1_b, nullptr, 1024, 4096);
  // y = h @ w2^T + b2 + y1  -> d_out
  gemm_bt<128, false, true, true, false, true, false>
      <<<dim3(64, 8, 1), 256, 0, stream>>>(h_b, w2b16, y_out, w2_b, y1, 4096, 1024);
}